// Round 1
// baseline (400.377 us; speedup 1.0000x reference)
//
#include <hip/hip_runtime.h>
#include <hip/hip_bf16.h>
#include <stdint.h>

// MoE: E=8 experts, M=4096 tokens, K=2048 hidden, I=1408 intermediate, TOPK=2
#define EXPERTS 8
#define MTOK 4096
#define KDIM 2048
#define IDIM 1408
#define NDIM 2816   // 2*I
#define CAP  8192   // per-expert bucket capacity (worst case: all pairs one expert)

typedef __attribute__((ext_vector_type(8))) short bf16x8;
typedef __attribute__((ext_vector_type(4))) float f32x4;

__device__ __forceinline__ unsigned short f2bf(float x) {
    unsigned u = __float_as_uint(x);
    u = u + 0x7fffu + ((u >> 16) & 1u);   // RNE
    return (unsigned short)(u >> 16);
}

__device__ __forceinline__ void gload16(const void* g, void* l) {
    __builtin_amdgcn_global_load_lds(
        (const __attribute__((address_space(1))) void*)g,
        (__attribute__((address_space(3))) void*)l, 16, 0, 0);
}

// ---------------- fp32 -> bf16 conversion (vectorized) ----------------
__global__ void __launch_bounds__(256) conv_bf16(const float* __restrict__ src,
                                                 unsigned short* __restrict__ dst, int n4) {
    int i = blockIdx.x * 256 + threadIdx.x;
    int st = gridDim.x * 256;
    for (; i < n4; i += st) {
        float4 v = reinterpret_cast<const float4*>(src)[i];
        ushort4 r;
        r.x = f2bf(v.x); r.y = f2bf(v.y); r.z = f2bf(v.z); r.w = f2bf(v.w);
        reinterpret_cast<ushort4*>(dst)[i] = r;
    }
}

// ---------------- router: bucket tokens per expert ----------------
__global__ void __launch_bounds__(256) router(const float* __restrict__ tw,
                                              const int* __restrict__ ids,
                                              int* __restrict__ tok, float* __restrict__ wgt,
                                              int* __restrict__ cnt) {
    int m = blockIdx.x * 256 + threadIdx.x;
    if (m >= MTOK) return;
#pragma unroll
    for (int t = 0; t < 2; t++) {
        int e = ids[m * 2 + t];
        int slot = atomicAdd(&cnt[e], 1);
        tok[e * CAP + slot] = m;
        wgt[e * CAP + slot] = tw[m * 2 + t];
    }
}

__global__ void scan_off(const int* __restrict__ cnt, int* __restrict__ off) {
    if (threadIdx.x == 0) {
        int s = 0;
        for (int e = 0; e < EXPERTS; e++) { off[e] = s; s += cnt[e]; }
    }
}

// ---------------- GEMM1 + SiLU*up -> act (bf16) ----------------
// Tile 128 rows x (64 gate + 64 up interleaved per 16-col fragment), BK=32.
// B-tile row r: group G=r>>4 even -> gate row, odd -> up row (same 16-col slice).
__global__ void __launch_bounds__(256) gemm1_silu(
    const unsigned short* __restrict__ hsb,
    const unsigned short* __restrict__ w1b,
    const int* __restrict__ tok,
    const int* __restrict__ cnt,
    const int* __restrict__ off,
    unsigned short* __restrict__ act) {
    const int cb = blockIdx.x;   // 0..21  (22 * 64 = 1408 gate cols)
    const int rb = blockIdx.y;   // 0..63  worst-case row blocks
    const int e  = blockIdx.z;
    const int cnt_e = cnt[e];
    if (rb * 128 >= cnt_e) return;
    const int off_e = off[e];

    __shared__ unsigned short As[128 * 32];  // 8KB [row][64B], swizzled slots
    __shared__ unsigned short Bs[128 * 32];
    __shared__ int toks[128];

    const int tid = threadIdx.x;
    const int w = tid >> 6, lane = tid & 63;
    if (tid < 128) {
        int slot = rb * 128 + tid;
        toks[tid] = (slot < cnt_e) ? tok[e * CAP + slot] : 0;
    }
    __syncthreads();

    // staging geometry: two 16B chunks per thread; linear LDS dest,
    // source k-group pre-swizzled: g = s ^ ((row>>1)&3)
    const int o0 = w * 1024 + lane * 16;
    const int row0 = o0 >> 6, g0 = ((o0 >> 4) & 3) ^ ((row0 >> 1) & 3);
    const int o1 = 4096 + o0;
    const int row1 = o1 >> 6, g1 = ((o1 >> 4) & 3) ^ ((row1 >> 1) & 3);

    const int G0 = row0 >> 4, G1 = row1 >> 4;
    const size_t w1base = (size_t)e * NDIM * KDIM;
    const int wrow0 = ((G0 & 1) ? IDIM : 0) + cb * 64 + (G0 >> 1) * 16 + (row0 & 15);
    const int wrow1 = ((G1 & 1) ? IDIM : 0) + cb * 64 + (G1 >> 1) * 16 + (row1 & 15);

    const int wr = w >> 1, wc = w & 1;
    const int l16 = lane & 15, lg = lane >> 4;

    f32x4 acc[4][4];
#pragma unroll
    for (int m = 0; m < 4; m++)
#pragma unroll
        for (int n = 0; n < 4; n++) acc[m][n] = {0.f, 0.f, 0.f, 0.f};

    char* Ab = (char*)As;
    char* Bb = (char*)Bs;
    const size_t srcA0 = (size_t)toks[row0] * KDIM + g0 * 8;
    const size_t srcA1 = (size_t)toks[row1] * KDIM + g1 * 8;
    const size_t srcB0 = w1base + (size_t)wrow0 * KDIM + g0 * 8;
    const size_t srcB1 = w1base + (size_t)wrow1 * KDIM + g1 * 8;

    for (int kt = 0; kt < KDIM / 32; ++kt) {
        const int kof = kt * 32;
        gload16(hsb + srcA0 + kof, Ab + w * 1024);
        gload16(hsb + srcA1 + kof, Ab + 4096 + w * 1024);
        gload16(w1b + srcB0 + kof, Bb + w * 1024);
        gload16(w1b + srcB1 + kof, Bb + 4096 + w * 1024);
        __syncthreads();

        bf16x8 a[4], b[4];
#pragma unroll
        for (int m = 0; m < 4; m++) {
            int r = wr * 64 + m * 16 + l16;
            a[m] = *reinterpret_cast<bf16x8*>(Ab + r * 64 + ((lg ^ ((r >> 1) & 3)) * 16));
        }
#pragma unroll
        for (int n = 0; n < 4; n++) {
            int r = wc * 64 + n * 16 + l16;
            b[n] = *reinterpret_cast<bf16x8*>(Bb + r * 64 + ((lg ^ ((r >> 1) & 3)) * 16));
        }
#pragma unroll
        for (int m = 0; m < 4; m++)
#pragma unroll
            for (int n = 0; n < 4; n++)
                acc[m][n] = __builtin_amdgcn_mfma_f32_16x16x32_bf16(a[m], b[n], acc[m][n], 0, 0, 0);
        __syncthreads();
    }

    // epilogue: n even = gate frag, n+1 = up frag (same 16 cols)
#pragma unroll
    for (int m = 0; m < 4; m++) {
#pragma unroll
        for (int np = 0; np < 2; np++) {
            f32x4 g4 = acc[m][np * 2];
            f32x4 u4 = acc[m][np * 2 + 1];
            int icol = cb * 64 + (wc * 2 + np) * 16 + l16;
#pragma unroll
            for (int j = 0; j < 4; j++) {
                int grow = rb * 128 + wr * 64 + m * 16 + lg * 4 + j;
                if (grow < cnt_e) {
                    float gt = g4[j], up = u4[j];
                    float s = gt / (1.f + __expf(-gt));
                    act[(size_t)(off_e + grow) * IDIM + icol] = f2bf(s * up);
                }
            }
        }
    }
}

// ---------------- GEMM2 + weighted scatter to out ----------------
__global__ void __launch_bounds__(256) gemm2_scatter(
    const unsigned short* __restrict__ act,
    const unsigned short* __restrict__ w2b,
    const int* __restrict__ tok,
    const float* __restrict__ wgt,
    const int* __restrict__ cnt,
    const int* __restrict__ off,
    float* __restrict__ out) {
    const int cb = blockIdx.x;   // 0..15 (16*128 = 2048 out cols)
    const int rb = blockIdx.y;
    const int e  = blockIdx.z;
    const int cnt_e = cnt[e];
    if (rb * 128 >= cnt_e) return;
    const int off_e = off[e];

    __shared__ unsigned short As[128 * 32];
    __shared__ unsigned short Bs[128 * 32];
    __shared__ int toks[128];
    __shared__ float wgts[128];

    const int tid = threadIdx.x;
    const int w = tid >> 6, lane = tid & 63;
    if (tid < 128) {
        int slot = rb * 128 + tid;
        bool v = slot < cnt_e;
        toks[tid] = v ? tok[e * CAP + slot] : 0;
        wgts[tid] = v ? wgt[e * CAP + slot] : 0.f;
    }
    __syncthreads();

    const int o0 = w * 1024 + lane * 16;
    const int row0 = o0 >> 6, g0 = ((o0 >> 4) & 3) ^ ((row0 >> 1) & 3);
    const int o1 = 4096 + o0;
    const int row1 = o1 >> 6, g1 = ((o1 >> 4) & 3) ^ ((row1 >> 1) & 3);

    const int s0 = rb * 128 + row0, s1 = rb * 128 + row1;
    const size_t pa0 = (size_t)(off_e + (s0 < cnt_e ? s0 : 0)) * IDIM + g0 * 8;
    const size_t pa1 = (size_t)(off_e + (s1 < cnt_e ? s1 : 0)) * IDIM + g1 * 8;
    const size_t w2base = (size_t)e * KDIM * IDIM;
    const size_t pb0 = w2base + (size_t)(cb * 128 + row0) * IDIM + g0 * 8;
    const size_t pb1 = w2base + (size_t)(cb * 128 + row1) * IDIM + g1 * 8;

    const int wr = w >> 1, wc = w & 1;
    const int l16 = lane & 15, lg = lane >> 4;

    f32x4 acc[4][4];
#pragma unroll
    for (int m = 0; m < 4; m++)
#pragma unroll
        for (int n = 0; n < 4; n++) acc[m][n] = {0.f, 0.f, 0.f, 0.f};

    char* Ab = (char*)As;
    char* Bb = (char*)Bs;

    for (int kt = 0; kt < IDIM / 32; ++kt) {
        const int kof = kt * 32;
        gload16(act + pa0 + kof, Ab + w * 1024);
        gload16(act + pa1 + kof, Ab + 4096 + w * 1024);
        gload16(w2b + pb0 + kof, Bb + w * 1024);
        gload16(w2b + pb1 + kof, Bb + 4096 + w * 1024);
        __syncthreads();

        bf16x8 a[4], b[4];
#pragma unroll
        for (int m = 0; m < 4; m++) {
            int r = wr * 64 + m * 16 + l16;
            a[m] = *reinterpret_cast<bf16x8*>(Ab + r * 64 + ((lg ^ ((r >> 1) & 3)) * 16));
        }
#pragma unroll
        for (int n = 0; n < 4; n++) {
            int r = wc * 64 + n * 16 + l16;
            b[n] = *reinterpret_cast<bf16x8*>(Bb + r * 64 + ((lg ^ ((r >> 1) & 3)) * 16));
        }
#pragma unroll
        for (int m = 0; m < 4; m++)
#pragma unroll
            for (int n = 0; n < 4; n++)
                acc[m][n] = __builtin_amdgcn_mfma_f32_16x16x32_bf16(a[m], b[n], acc[m][n], 0, 0, 0);
        __syncthreads();
    }

    // scatter: out[token, k] += weight * y  (TOPK=2 -> commutative fp32 add, deterministic)
#pragma unroll
    for (int m = 0; m < 4; m++) {
#pragma unroll
        for (int n = 0; n < 4; n++) {
            int kcol = cb * 128 + wc * 64 + n * 16 + l16;
#pragma unroll
            for (int j = 0; j < 4; j++) {
                int lrow = wr * 64 + m * 16 + lg * 4 + j;
                if (rb * 128 + lrow < cnt_e) {
                    atomicAdd(&out[(size_t)toks[lrow] * KDIM + kcol],
                              wgts[lrow] * acc[m][n][j]);
                }
            }
        }
    }
}

extern "C" void kernel_launch(void* const* d_in, const int* in_sizes, int n_in,
                              void* d_out, int out_size, void* d_ws, size_t ws_size,
                              hipStream_t stream) {
    const float* hs  = (const float*)d_in[0];
    const float* w1  = (const float*)d_in[1];
    const float* w2  = (const float*)d_in[2];
    const float* tw  = (const float*)d_in[3];
    const int*   ids = (const int*)d_in[4];
    float* out = (float*)d_out;

    // ws layout (bytes, 256-aligned)
    char* ws = (char*)d_ws;
    unsigned short* w1b  = (unsigned short*)(ws);                  //  92,274,688
    unsigned short* w2b  = (unsigned short*)(ws + 92274688ull);    //  46,137,344
    unsigned short* hsb  = (unsigned short*)(ws + 138412032ull);   //  16,777,216
    unsigned short* actb = (unsigned short*)(ws + 155189248ull);   //  23,068,672
    int*   tokb = (int*)  (ws + 178257920ull);                     //     262,144
    float* wgtb = (float*)(ws + 178520064ull);                     //     262,144
    int*   cntb = (int*)  (ws + 178782208ull);                     //          32
    int*   offb = (int*)  (ws + 178782240ull);                     //          32

    hipMemsetAsync(d_out, 0, (size_t)MTOK * KDIM * sizeof(float), stream);
    hipMemsetAsync(cntb, 0, 64, stream);

    conv_bf16<<<4096, 256, 0, stream>>>(w1, w1b, EXPERTS * NDIM * KDIM / 4);
    conv_bf16<<<2048, 256, 0, stream>>>(w2, w2b, EXPERTS * KDIM * IDIM / 4);
    conv_bf16<<<1024, 256, 0, stream>>>(hs, hsb, MTOK * KDIM / 4);

    router<<<MTOK / 256, 256, 0, stream>>>(tw, ids, tokb, wgtb, cntb);
    scan_off<<<1, 64, 0, stream>>>(cntb, offb);

    gemm1_silu<<<dim3(22, 64, 8), 256, 0, stream>>>(hsb, w1b, tokb, cntb, offb, actb);
    gemm2_scatter<<<dim3(16, 64, 8), 256, 0, stream>>>(actb, w2b, tokb, wgtb, cntb, offb, out);
}